// Round 7
// baseline (584.436 us; speedup 1.0000x reference)
//
#include <hip/hip_runtime.h>

// WaveNet block: B=16, C=256, T=4096, LAYERS=8, K=2 (causal, dilation 2^l).
// Stacked single-GEMM per layer: filter+gate rows interleaved at 16-row
// granularity (M=512), N=B*T, K=512. BM=128(stk) x BN=128, 4 waves,
// wave-tile 64x64, acc=64 AGPR.
// r7 KEY: one-barrier K-step. 3-slab LDS rotation (48 KB): STAGE(kk+2)
// overwrites the slab read at kk-1 (its readers crossed barrier kk-1),
// so the read-protection barrier is gone. Step = ds_read -> STAGE(kk+2)
// -> MFMA -> vmcnt(4) -> s_barrier. Counted vmcnt never drains mid-loop.
// Z: fold into fp32 Zacc[b][t][c]; quad-fold ({x1..x4}@l3, {x5..x8}@l7,
// Zacc 192 MB) when ws fits 4 X buffers, else tri-fold, else pair-fold.
// Zacc lives in ws when it fits (kills the copy4 tail pass).

typedef __attribute__((ext_vector_type(8))) short s16x8;
typedef __attribute__((ext_vector_type(4))) short s16x4;
typedef __attribute__((ext_vector_type(4))) float f32x4;

#define NB 16
#define NC 256
#define NT 4096
#define TPAD 4224   // 128 (zero pad) + 4096
#define PADT 128
#define NLAYERS 8
#define KTOT 512    // C * Ktap
#define MSTK 512    // stacked rows: f/g interleaved at 16-row granularity

__device__ __forceinline__ short f2bf(float x) {
  union { float f; unsigned u; } v; v.f = x;
  unsigned u = v.u;
  unsigned r = (u + 0x7fffu + ((u >> 16) & 1u)) >> 16;  // RNE
  return (short)r;
}
__device__ __forceinline__ float bf2f(short s) {
  union { float f; unsigned u; } v; v.u = ((unsigned)(unsigned short)s) << 16;
  return v.f;
}

__device__ __forceinline__ void async16(short* lp, const short* gp) {
  __builtin_amdgcn_global_load_lds(
      (const __attribute__((address_space(1))) unsigned int*)gp,
      (__attribute__((address_space(3))) unsigned int*)lp,
      16, 0, 0);
}

// ---------------- prep kernels ----------------

// zero the t<0 pad region of nbuf consecutive X buffers (ws is poisoned 0xAA)
__global__ void zero_pads(short* __restrict__ base, int nbuf, size_t strideSh) {
  int idx = blockIdx.x * 256 + threadIdx.x;    // over nbuf * NB*PADT*NC
  if (idx >= nbuf * NB * PADT * NC) return;
  int j = idx >> 19;                            // / (NB*PADT*NC = 524288)
  int rem = idx & 524287;
  int b = rem >> 15;                            // / (PADT*NC)
  int r2 = rem & 32767;
  base[(size_t)j * strideSh + (size_t)b * TPAD * NC + r2] = 0;
}

// ys [b][c][t] fp32  ->  X0 [b][128+t][c] bf16 (LDS-tiled transpose)
__global__ void transpose_cast(const float* __restrict__ ys, short* __restrict__ X0) {
  __shared__ float tile[64][65];
  const int b = blockIdx.z, c0 = blockIdx.y * 64, t0 = blockIdx.x * 64;
  const int tid = threadIdx.x;
#pragma unroll
  for (int i = 0; i < 16; ++i) {
    int c = (tid >> 6) + i * 4;
    int t = tid & 63;
    tile[c][t] = ys[((size_t)(b * NC + c0 + c)) * NT + t0 + t];
  }
  __syncthreads();
#pragma unroll
  for (int i = 0; i < 2; ++i) {
    int q = tid + i * 256;                      // 512 chunks of 8 bf16
    int t = q >> 3, cc = (q & 7) * 8;
    s16x8 v;
#pragma unroll
    for (int j = 0; j < 8; ++j) v[j] = f2bf(tile[cc + j][t]);
    *(s16x8*)&X0[((size_t)(b * TPAD + PADT + t0 + t)) * NC + c0 + cc] = v;
  }
}

// weights [l][co][ci][kw] fp32 -> stacked interleaved Ws[l][r][k] bf16
// r = j*32 + s*16 + c16  (channel = j*16+c16, s: 0=filter 1=gate), k = kw*256+ci
__global__ void convert_w(const float* __restrict__ fw, const float* __restrict__ gw,
                          short* __restrict__ Ws) {
  int idx = blockIdx.x * 256 + threadIdx.x;     // over 8*512*512 = 2097152
  if (idx >= NLAYERS * MSTK * KTOT) return;
  int k = idx & (KTOT - 1);
  int r = (idx >> 9) & (MSTK - 1);
  int l = idx >> 18;
  int kw = k >> 8, ci = k & 255;
  int j = r >> 5, s = (r >> 4) & 1, c16 = r & 15;
  int ch = j * 16 + c16;
  int src = ((l * NC + ch) * NC + ci) * 2 + kw;
  Ws[idx] = f2bf(s ? gw[src] : fw[src]);
}

// ---------------- fused layer kernel ----------------
// grid (4, 32, 16): m-tile (64 channels, f+g stacked = 128 rows),
// t-tile (128), batch.  256 threads = 4 waves (2M x 2N), wave-tile 64x64.
// zmode: 0 = none; 1 = Zacc store; 2 = Zacc rmw.  Fold sum = z + bf2f(Xin)
// (+ bf2f(Xp1)) (+ bf2f(Xp2)).
__global__ __launch_bounds__(256, 2)
void wavenet_layer(const short* __restrict__ Xin, short* __restrict__ Xout,
                   const short* __restrict__ Wl,
                   const float* __restrict__ bia_f, const float* __restrict__ bia_g,
                   float* __restrict__ Z,
                   const short* __restrict__ Xp1, const short* __restrict__ Xp2,
                   int d, int zmode, int writeX) {
  __shared__ short lds[24576];                  // 48 KB: A0 A1 A2 B0 B1 B2 (8 KB)

  const int tid = threadIdx.x;
  const int wave = tid >> 6, lane = tid & 63;
  const int quad = lane >> 4, l16 = lane & 15;
  const int wm = wave >> 1, wn = wave & 1;

  // XCD swizzle: give each XCD a contiguous logical range (= 2 batches,
  // all mt/ty) so same-X blocks share one L2 (~4.3 MB working set).
  int flat = blockIdx.x + 4 * (blockIdx.y + 32 * blockIdx.z);   // 0..2047
  int swz = (flat & 7) * 256 + (flat >> 3);                     // bijective
  const int mt = swz & 3;
  const int ty = (swz >> 2) & 31;
  const int b  = swz >> 7;
  const int m0s = mt * 128;                     // stacked-row base
  const int t0  = ty * 128;

  const short* Wm = Wl + (size_t)m0s * KTOT;
  const short* Xb = Xin + ((size_t)b * TPAD + PADT + t0) * NC;

  f32x4 acc[4][4] = {};
  // read-side swizzled chunk: row bits 2:1 (bit0 aliases the row-parity
  // bank bit and collapses a 16-lane phase group to 4 bank groups)
  const int xo = (quad ^ ((l16 >> 1) & 3)) * 8;

  // stage one BK=32 K-slab (A: 128x32, B: 128x32) into rotation slot `buf`
  auto STAGE = [&](int buf, int kk) {
    short* Ad = lds + buf * 4096;
    short* Bd = lds + 12288 + buf * 4096;
    const int kw = kk >> 3;
    const int ci0 = (kk & 7) * 32;
    const int k0 = kw * 256 + ci0;
    const int tsh = (kw == 0) ? -d : 0;         // tap 0 reads x[t-d]
#pragma unroll
    for (int i = 0; i < 2; ++i) {
      int q = i * 256 + tid;                    // physical chunk 0..511
      int r = q >> 2;                           // row 0..127
      int kc = ((q & 3) ^ ((r >> 1) & 3)) * 8;  // swizzled source chunk
      async16(Ad + q * 8, Wm + r * KTOT + k0 + kc);
      async16(Bd + q * 8, Xb + (r + tsh) * NC + ci0 + kc);   // tsh<0 ok
    }
  };

  // prologue: slabs 0,1 in flight; wait only for slab 0
  STAGE(0, 0);
  STAGE(1, 1);
  asm volatile("s_waitcnt vmcnt(4)" ::: "memory");
  __builtin_amdgcn_sched_barrier(0);
  __builtin_amdgcn_s_barrier();

  // K-loop: 16 steps, ONE barrier per step. STAGE(kk+2) overwrites the slab
  // read at step kk-1 -- its readers crossed barrier kk-1, so no extra
  // barrier is needed. vmcnt(4) = slab kk+1 landed (4 loads/thread/slab).
#pragma unroll
  for (int kk = 0; kk < 16; ++kk) {
    const int cur = kk % 3;
    const short* Ar = lds + cur * 4096;
    const short* Br = lds + 12288 + cur * 4096;
    s16x8 bfr[4];
#pragma unroll
    for (int ni = 0; ni < 4; ++ni)
      bfr[ni] = *(const s16x8*)&Br[(wn * 64 + ni * 16 + l16) * 32 + xo];
    if (kk < 14) STAGE((kk + 2) % 3, kk + 2);
    __builtin_amdgcn_s_setprio(1);
#pragma unroll
    for (int mi = 0; mi < 4; ++mi) {
      s16x8 af = *(const s16x8*)&Ar[(wm * 64 + mi * 16 + l16) * 32 + xo];
#pragma unroll
      for (int ni = 0; ni < 4; ++ni)
        acc[mi][ni] = __builtin_amdgcn_mfma_f32_16x16x32_bf16(af, bfr[ni], acc[mi][ni], 0, 0, 0);
    }
    __builtin_amdgcn_s_setprio(0);
    if (kk == 15) break;
    if (kk < 14) asm volatile("s_waitcnt vmcnt(4)" ::: "memory");
    else         asm volatile("s_waitcnt vmcnt(0)" ::: "memory");
    __builtin_amdgcn_sched_barrier(0);
    __builtin_amdgcn_s_barrier();
    __builtin_amdgcn_sched_barrier(0);
  }
  __syncthreads();                              // all LDS reads done; reuse as ZT

  // ---------------- epilogue ----------------
  // mi even = filter rows, mi odd = gate rows of the SAME channels (in-thread).
  short* ZT = lds;                              // reuse: [128 t][64 c] rotated

#pragma unroll
  for (int p = 0; p < 2; ++p) {
    const int cloc = (wm * 2 + p) * 16 + quad * 4;   // local channel base 0..60
    const int ch = mt * 64 + cloc;                   // global channel base
    float4 bf4 = *(const float4*)&bia_f[ch];
    float4 bg4 = *(const float4*)&bia_g[ch];
    const float* bfp = (const float*)&bf4;
    const float* bgp = (const float*)&bg4;
#pragma unroll
    for (int ni = 0; ni < 4; ++ni) {
      const int tl = wn * 64 + ni * 16 + l16;        // tile-local time 0..127
      short pk[4];
#pragma unroll
      for (int r = 0; r < 4; ++r) {
        float f = acc[2 * p][ni][r] + bfp[r];
        float g = acc[2 * p + 1][ni][r] + bgp[r];
        float ef = __expf(2.f * f);
        float th = 1.f - 2.f / (ef + 1.f);           // tanh, no-overflow form
        float sg = 1.f / (1.f + __expf(-g));
        pk[r] = f2bf(th * sg);
      }
      // rotate-swizzle: physical col = (c + t*8) & 63 (stays 4-aligned)
      short* dst = &ZT[tl * 64 + ((cloc + tl * 8) & 63)];
      *(s16x4*)dst = (s16x4){pk[0], pk[1], pk[2], pk[3]};
    }
  }
  __syncthreads();
#pragma unroll
  for (int i = 0; i < 4; ++i) {                  // 1024 chunks of 16B (128 t rows)
    int q = tid + i * 256;
    int t = q >> 3, cc = (q & 7) * 8;
    s16x8 v = *(const s16x8*)&ZT[t * 64 + ((cc + t * 8) & 63)];
    const size_t xoff = ((size_t)(b * TPAD + PADT + t0 + t)) * NC + mt * 64 + cc;
    if (writeX) *(s16x8*)&Xout[xoff] = v;
    if (zmode) {
      // fold: z + Xin (+ Xp1) (+ Xp2) into fp32 Zacc[b][t][c]
      s16x8 xv = *(const s16x8*)&Xin[xoff];
      float zv[8];
#pragma unroll
      for (int j = 0; j < 8; ++j) zv[j] = bf2f(v[j]) + bf2f(xv[j]);
      if (Xp1) {
        s16x8 pv = *(const s16x8*)&Xp1[xoff];
#pragma unroll
        for (int j = 0; j < 8; ++j) zv[j] += bf2f(pv[j]);
      }
      if (Xp2) {
        s16x8 pv = *(const s16x8*)&Xp2[xoff];
#pragma unroll
        for (int j = 0; j < 8; ++j) zv[j] += bf2f(pv[j]);
      }
      size_t zo = ((size_t)b * NT + t0 + t) * NC + mt * 64 + cc;
      if (zmode == 2) {
        float4 a0 = *(const float4*)&Z[zo];
        float4 a1 = *(const float4*)&Z[zo + 4];
        zv[0] += a0.x; zv[1] += a0.y; zv[2] += a0.z; zv[3] += a0.w;
        zv[4] += a1.x; zv[5] += a1.y; zv[6] += a1.z; zv[7] += a1.w;
      }
      *(float4*)&Z[zo]     = make_float4(zv[0], zv[1], zv[2], zv[3]);
      *(float4*)&Z[zo + 4] = make_float4(zv[4], zv[5], zv[6], zv[7]);
    }
  }
}

// ---------------- final: Zacc [b][t][c] fp32 -> dst [b][c][t] fp32 ----------------
__global__ void transpose_out(const float* __restrict__ src, float* __restrict__ dst) {
  __shared__ float tile[64][65];
  const int b = blockIdx.z, c0 = blockIdx.y * 64, t0 = blockIdx.x * 64;
  const int tid = threadIdx.x;
#pragma unroll
  for (int i = 0; i < 4; ++i) {
    int q = tid + i * 256;                      // 1024 float4 chunks
    int t = q >> 4, c = (q & 15) * 4;
    float4 v = *(const float4*)&src[((size_t)b * NT + t0 + t) * NC + c0 + c];
    tile[t][c] = v.x; tile[t][c + 1] = v.y; tile[t][c + 2] = v.z; tile[t][c + 3] = v.w;
  }
  __syncthreads();
#pragma unroll
  for (int i = 0; i < 4; ++i) {
    int q = tid + i * 256;
    int c = q >> 4, t = (q & 15) * 4;
    float4 v = make_float4(tile[t][c], tile[t + 1][c], tile[t + 2][c], tile[t + 3][c]);
    *(float4*)&dst[((size_t)b * NC + c0 + c) * NT + t0 + t] = v;
  }
}

__global__ void copy4(const float4* __restrict__ s, float4* __restrict__ d, int n) {
  int i = blockIdx.x * 256 + threadIdx.x;
  int stride = gridDim.x * 256;
  for (; i < n; i += stride) d[i] = s[i];
}

// ---------------- launch ----------------
extern "C" void kernel_launch(void* const* d_in, const int* in_sizes, int n_in,
                              void* d_out, int out_size, void* d_ws, size_t ws_size,
                              hipStream_t stream) {
  const float* ys = (const float*)d_in[0];
  const float* fw = (const float*)d_in[1];
  const float* fb = (const float*)d_in[2];
  const float* gw = (const float*)d_in[3];
  const float* gb = (const float*)d_in[4];
  float* Zout = (float*)d_out;

  char* ws = (char*)d_ws;
  const size_t xbytes = (size_t)NB * TPAD * NC * 2;      // 34.6 MB each
  const size_t strideSh = xbytes / 2;                    // shorts per X buffer
  const size_t wbytes = (size_t)NLAYERS * MSTK * KTOT * 2;   // 4.2 MB
  const size_t zbytes = (size_t)NB * NC * NT * 4;        // 64 MB fp32 Zacc

  // tier chain: prefer quad-fold (192 MB Zacc traffic) and Zacc-in-ws
  // (no copy4 tail).  quad+dout == tri+ws in total traffic; tri+ws simpler.
  int nxb, zws;
  if      (ws_size >= 4 * xbytes + wbytes + zbytes) { nxb = 4; zws = 1; }
  else if (ws_size >= 3 * xbytes + wbytes + zbytes) { nxb = 3; zws = 1; }
  else if (ws_size >= 4 * xbytes + wbytes)          { nxb = 4; zws = 0; }
  else if (ws_size >= 3 * xbytes + wbytes)          { nxb = 3; zws = 0; }
  else                                              { nxb = 2; zws = 0; }

  short* Xbase = (short*)ws;
  short* Ws = (short*)(ws + (size_t)nxb * xbytes);
  float* Zacc = zws ? (float*)(ws + (size_t)nxb * xbytes + wbytes) : Zout;

  {
    int total = nxb * NB * PADT * NC;
    hipLaunchKernelGGL(zero_pads, dim3((total + 255) / 256), dim3(256), 0, stream,
                       Xbase, nxb, strideSh);
  }
  hipLaunchKernelGGL(transpose_cast, dim3(64, 4, 16), dim3(256), 0, stream, ys, Xbase);
  hipLaunchKernelGGL(convert_w, dim3(8192), dim3(256), 0, stream, fw, gw, Ws);

  for (int l = 0; l < NLAYERS; ++l) {
    const short* Xin;
    short* Xo;
    int zmode = 0;
    const short* Xp1 = nullptr;
    const short* Xp2 = nullptr;
    if (nxb >= 3) {
      Xin = Xbase + (size_t)(l % nxb) * strideSh;
      Xo  = Xbase + (size_t)((l + 1) % nxb) * strideSh;
      if (nxb == 4) {
        // quad-fold: l=3 {x1,x2,x3,z4} store; l=7 {x5,x6,x7,z8} rmw
        if (l == 3 || l == 7) {
          zmode = (l == 3) ? 1 : 2;
          Xp1 = Xbase + 2 * strideSh;           // x2 / x6
          Xp2 = Xbase + 1 * strideSh;           // x1 / x5
        }
      } else {
        // tri-fold: l=2 {x1,x2,z3} store; l=5 {x4,x5,z6} rmw; l=7 {x7,z8} rmw
        if (l == 2)      { zmode = 1; Xp1 = Xbase + strideSh; }
        else if (l == 5) { zmode = 2; Xp1 = Xbase + strideSh; }
        else if (l == 7) { zmode = 2; }
      }
    } else {
      // 2-buffer ping-pong, pair-fold: odd layers fold {x_l, z_{l+1}}
      Xin = (l & 1) ? Xbase + strideSh : Xbase;
      Xo  = (l & 1) ? Xbase : Xbase + strideSh;
      zmode = (l & 1) ? ((l == 1) ? 1 : 2) : 0;
    }
    int writeX = (l < NLAYERS - 1) ? 1 : 0;
    hipLaunchKernelGGL(wavenet_layer, dim3(4, 32, 16), dim3(256), 0, stream,
                       Xin, Xo,
                       Ws + (size_t)l * MSTK * KTOT,
                       fb + l * NC, gb + l * NC, Zacc, Xp1, Xp2,
                       1 << l, zmode, writeX);
  }

  if (zws) {
    hipLaunchKernelGGL(transpose_out, dim3(64, 4, 16), dim3(256), 0, stream,
                       Zacc, Zout);
  } else {
    // Zacc lives in d_out; transpose into the freed X area (fp32, 64 MB fits
    // in the first two X buffers = 69 MB), then copy back to d_out.
    float* tmp = (float*)ws;
    hipLaunchKernelGGL(transpose_out, dim3(64, 4, 16), dim3(256), 0, stream,
                       Zacc, tmp);
    int n4 = (int)(zbytes / 16);
    hipLaunchKernelGGL(copy4, dim3(2048), dim3(256), 0, stream,
                       (const float4*)tmp, (float4*)Zout, n4);
  }
}